// Round 2
// baseline (152.599 us; speedup 1.0000x reference)
//
#include <hip/hip_runtime.h>

#define BATCH 8
#define CH 3
#define H_OUT 384
#define W_OUT 1280
#define H_IN 96
#define W_IN 320
#define HW_OUT (H_OUT * W_OUT)
#define HW_IN (H_IN * W_IN)
#define PXT 4   // pixels per thread -> 320 threads per row-block

__global__ __launch_bounds__(320) void warp_sceneflow_kernel(
    const float* __restrict__ image,   // (B,3,384,1280)
    const float* __restrict__ disp,    // (B,1,96,320)
    const float* __restrict__ scene,   // (B,3,96,320)
    const float* __restrict__ intrin,  // (B,3,3)
    const float* __restrict__ aug,     // (B,2)
    float* __restrict__ out)           // (B,3,384,1280)
{
    // One block = one output row (b, y). 3072 blocks round-robin across the
    // 8 XCDs by bid%8, so taking b = bid&7 gives each XCD exactly one batch:
    // per-XCD L2 streams a single 5.9 MB image slice once (kills the 4.3x
    // duplicate FETCH seen in R0).
    int bid = blockIdx.x;
    int b = bid & 7;
    int y = bid >> 3;

    // per-batch scaled intrinsics (uniform across block -> scalar broadcast)
    float sy = (float)H_OUT / aug[b * 2 + 0];
    float sx = (float)W_OUT / aug[b * 2 + 1];
    float fx = intrin[b * 9 + 0] * sx;
    float fy = intrin[b * 9 + 4] * sy;
    float cx = intrin[b * 9 + 2] * sx;
    float cy = intrin[b * 9 + 5] * sy;
    float inv_fx = 1.0f / fx;
    float inv_fy = 1.0f / fy;

    // row-wise bilinear source coords for the low-res maps (uniform in block)
    float ysrc = (float)y * ((float)(H_IN - 1) / (float)(H_OUT - 1));
    int y0 = (int)ysrc;
    int y1 = min(y0 + 1, H_IN - 1);
    float wy = ysrc - (float)y0;

    const float* db = disp + b * HW_IN;
    const float* sb = scene + b * (CH * HW_IN);
    const float* ib = image + b * (CH * HW_OUT);
    float* ob = out + b * (CH * HW_OUT) + y * W_OUT;

    int xbase = threadIdx.x * PXT;

    float res0[PXT], res1[PXT], res2[PXT];

    #pragma unroll
    for (int k = 0; k < PXT; ++k) {
        int x = xbase + k;
        float xsrc = (float)x * ((float)(W_IN - 1) / (float)(W_OUT - 1));
        int x0 = (int)xsrc;
        int x1 = min(x0 + 1, W_IN - 1);
        float wx = xsrc - (float)x0;
        float w00 = (1.0f - wy) * (1.0f - wx);
        float w01 = (1.0f - wy) * wx;
        float w10 = wy * (1.0f - wx);
        float w11 = wy * wx;

        // disp upsample -> depth
        float dval = w00 * db[y0 * W_IN + x0] + w01 * db[y0 * W_IN + x1]
                   + w10 * db[y1 * W_IN + x0] + w11 * db[y1 * W_IN + x1];
        float disp_full = dval * (float)W_OUT;
        float depth = fminf(fmaxf(fx * 0.54f / (disp_full + 1e-8f), 0.001f), 80.0f);

        // scene upsample (3 channels, same weights)
        const float* s0 = sb;
        const float* s1 = sb + HW_IN;
        const float* s2 = sb + 2 * HW_IN;
        int i00 = y0 * W_IN + x0, i01 = y0 * W_IN + x1;
        int i10 = y1 * W_IN + x0, i11 = y1 * W_IN + x1;
        float sc0 = w00 * s0[i00] + w01 * s0[i01] + w10 * s0[i10] + w11 * s0[i11];
        float sc1 = w00 * s1[i00] + w01 * s1[i01] + w10 * s1[i10] + w11 * s1[i11];
        float sc2 = w00 * s2[i00] + w01 * s2[i01] + w10 * s2[i10] + w11 * s2[i11];

        // backproject (Kinv analytic) + scene flow
        float X = ((float)x - cx) * inv_fx * depth + sc0;
        float Y = ((float)y - cy) * inv_fy * depth + sc1;
        float Z = depth + sc2;

        // reproject
        float u = fx * X + cx * Z;
        float v = fy * Y + cy * Z;
        float rw = 1.0f / (Z + 1e-8f);
        float coord_x = u * rw;
        float coord_y = v * rw;

        // normalize round-trip (matches reference arithmetic)
        float nx = coord_x / (float)(W_OUT - 1) * 2.0f - 1.0f;
        float ny = coord_y / (float)(H_OUT - 1) * 2.0f - 1.0f;
        float gx = (nx + 1.0f) * 0.5f * (float)(W_OUT - 1);
        float gy = (ny + 1.0f) * 0.5f * (float)(H_OUT - 1);

        // grid sample, zeros padding, bilinear
        float gx0f = floorf(gx), gy0f = floorf(gy);
        float fwx = gx - gx0f, fwy = gy - gy0f;
        int ix0 = (int)gx0f, iy0 = (int)gy0f;
        int ix1 = ix0 + 1, iy1 = iy0 + 1;
        bool vx0 = (ix0 >= 0) && (ix0 <= W_OUT - 1);
        bool vx1 = (ix1 >= 0) && (ix1 <= W_OUT - 1);
        bool vy0 = (iy0 >= 0) && (iy0 <= H_OUT - 1);
        bool vy1 = (iy1 >= 0) && (iy1 <= H_OUT - 1);
        int cx0 = min(max(ix0, 0), W_OUT - 1);
        int cx1 = min(max(ix1, 0), W_OUT - 1);
        int cy0 = min(max(iy0, 0), H_OUT - 1);
        int cy1 = min(max(iy1, 0), H_OUT - 1);
        float g00 = (1.0f - fwy) * (1.0f - fwx) * ((vx0 && vy0) ? 1.0f : 0.0f);
        float g01 = (1.0f - fwy) * fwx * ((vx1 && vy0) ? 1.0f : 0.0f);
        float g10 = fwy * (1.0f - fwx) * ((vx0 && vy1) ? 1.0f : 0.0f);
        float g11 = fwy * fwx * ((vx1 && vy1) ? 1.0f : 0.0f);

        int o00 = cy0 * W_OUT + cx0;
        int o01 = cy0 * W_OUT + cx1;
        int o10 = cy1 * W_OUT + cx0;
        int o11 = cy1 * W_OUT + cx1;

        const float* im0 = ib;
        const float* im1 = ib + HW_OUT;
        const float* im2 = ib + 2 * HW_OUT;
        res0[k] = g00 * im0[o00] + g01 * im0[o01] + g10 * im0[o10] + g11 * im0[o11];
        res1[k] = g00 * im1[o00] + g01 * im1[o01] + g10 * im1[o10] + g11 * im1[o11];
        res2[k] = g00 * im2[o00] + g01 * im2[o01] + g10 * im2[o10] + g11 * im2[o11];
    }

    // coalesced float4 stores per channel
    *reinterpret_cast<float4*>(ob + xbase) =
        make_float4(res0[0], res0[1], res0[2], res0[3]);
    *reinterpret_cast<float4*>(ob + HW_OUT + xbase) =
        make_float4(res1[0], res1[1], res1[2], res1[3]);
    *reinterpret_cast<float4*>(ob + 2 * HW_OUT + xbase) =
        make_float4(res2[0], res2[1], res2[2], res2[3]);
}

extern "C" void kernel_launch(void* const* d_in, const int* in_sizes, int n_in,
                              void* d_out, int out_size, void* d_ws, size_t ws_size,
                              hipStream_t stream) {
    const float* image  = (const float*)d_in[0];
    const float* disp   = (const float*)d_in[1];
    const float* scene  = (const float*)d_in[2];
    const float* intrin = (const float*)d_in[3];
    const float* aug    = (const float*)d_in[4];
    float* out = (float*)d_out;

    const int grid = BATCH * H_OUT;   // one block per output row
    const int block = W_OUT / PXT;    // 320 threads = 5 waves
    warp_sceneflow_kernel<<<grid, block, 0, stream>>>(image, disp, scene, intrin, aug, out);
}

// Round 3
// 92.753 us; speedup vs baseline: 1.6452x; 1.6452x over previous
//
#include <hip/hip_runtime.h>

#define BATCH 8
#define CH 3
#define H_OUT 384
#define W_OUT 1280
#define H_IN 96
#define W_IN 320
#define HW_OUT (H_OUT * W_OUT)
#define HW_IN (H_IN * W_IN)

// grid decomposition: 256 px per block, 5 blocks per row, 1920 chunks per batch
#define SEGS_PER_ROW (W_OUT / 256)   // 5
#define CHUNKS_PER_B (H_OUT * SEGS_PER_ROW)  // 1920

__global__ __launch_bounds__(256) void warp_sceneflow_kernel(
    const float* __restrict__ image,   // (B,3,384,1280)
    const float* __restrict__ disp,    // (B,1,96,320)
    const float* __restrict__ scene,   // (B,3,96,320)
    const float* __restrict__ intrin,  // (B,3,3)
    const float* __restrict__ aug,     // (B,2)
    float* __restrict__ out)           // (B,3,384,1280)
{
    // XCD-aware: blocks round-robin XCDs by bid%8, so b = bid&7 pins each
    // batch's working set (5.9 MB) to one XCD's L2 (keeps R1's 26 MB FETCH).
    // Within a batch, chunk = bid>>3 walks (y, xseg) in row-major order so
    // consecutive blocks on an XCD touch adjacent rows (L2-friendly).
    int bid = blockIdx.x;
    int b = bid & 7;
    int c = bid >> 3;              // 0..1919
    int y = c / SEGS_PER_ROW;
    int xseg = c - y * SEGS_PER_ROW;
    int x = xseg * 256 + threadIdx.x;   // wave lanes span 64 consecutive x

    // per-batch scaled intrinsics (uniform across block -> scalar broadcast)
    float sy = (float)H_OUT / aug[b * 2 + 0];
    float sx = (float)W_OUT / aug[b * 2 + 1];
    float fx = intrin[b * 9 + 0] * sx;
    float fy = intrin[b * 9 + 4] * sy;
    float cx = intrin[b * 9 + 2] * sx;
    float cy = intrin[b * 9 + 5] * sy;
    float inv_fx = 1.0f / fx;
    float inv_fy = 1.0f / fy;

    // bilinear source coords for the low-res maps
    float ysrc = (float)y * ((float)(H_IN - 1) / (float)(H_OUT - 1));
    int y0 = (int)ysrc;
    int y1 = min(y0 + 1, H_IN - 1);
    float wy = ysrc - (float)y0;

    float xsrc = (float)x * ((float)(W_IN - 1) / (float)(W_OUT - 1));
    int x0 = (int)xsrc;
    int x1 = min(x0 + 1, W_IN - 1);
    float wx = xsrc - (float)x0;

    const float* db = disp + b * HW_IN;
    const float* sb = scene + b * (CH * HW_IN);
    int i00 = y0 * W_IN + x0, i01 = y0 * W_IN + x1;
    int i10 = y1 * W_IN + x0, i11 = y1 * W_IN + x1;

    // issue all 16 low-res loads early (independent, L1/L2-resident)
    float d00 = db[i00], d01 = db[i01], d10 = db[i10], d11 = db[i11];
    const float* s0 = sb;
    const float* s1 = sb + HW_IN;
    const float* s2 = sb + 2 * HW_IN;
    float a00 = s0[i00], a01 = s0[i01], a10 = s0[i10], a11 = s0[i11];
    float b00 = s1[i00], b01 = s1[i01], b10 = s1[i10], b11 = s1[i11];
    float e00 = s2[i00], e01 = s2[i01], e10 = s2[i10], e11 = s2[i11];

    float w00 = (1.0f - wy) * (1.0f - wx);
    float w01 = (1.0f - wy) * wx;
    float w10 = wy * (1.0f - wx);
    float w11 = wy * wx;

    float dval = w00 * d00 + w01 * d01 + w10 * d10 + w11 * d11;
    float disp_full = dval * (float)W_OUT;
    float depth = fminf(fmaxf(fx * 0.54f / (disp_full + 1e-8f), 0.001f), 80.0f);

    float sc0 = w00 * a00 + w01 * a01 + w10 * a10 + w11 * a11;
    float sc1 = w00 * b00 + w01 * b01 + w10 * b10 + w11 * b11;
    float sc2 = w00 * e00 + w01 * e01 + w10 * e10 + w11 * e11;

    // backproject (Kinv analytic) + scene flow
    float X = ((float)x - cx) * inv_fx * depth + sc0;
    float Y = ((float)y - cy) * inv_fy * depth + sc1;
    float Z = depth + sc2;

    // reproject
    float u = fx * X + cx * Z;
    float v = fy * Y + cy * Z;
    float rw = 1.0f / (Z + 1e-8f);
    float coord_x = u * rw;
    float coord_y = v * rw;

    // normalize round-trip (matches reference arithmetic)
    float nx = coord_x / (float)(W_OUT - 1) * 2.0f - 1.0f;
    float ny = coord_y / (float)(H_OUT - 1) * 2.0f - 1.0f;
    float gx = (nx + 1.0f) * 0.5f * (float)(W_OUT - 1);
    float gy = (ny + 1.0f) * 0.5f * (float)(H_OUT - 1);

    // grid sample, zeros padding, bilinear
    float gx0f = floorf(gx), gy0f = floorf(gy);
    float fwx = gx - gx0f, fwy = gy - gy0f;
    int ix0 = (int)gx0f, iy0 = (int)gy0f;
    int ix1 = ix0 + 1, iy1 = iy0 + 1;
    bool vx0 = (ix0 >= 0) && (ix0 <= W_OUT - 1);
    bool vx1 = (ix1 >= 0) && (ix1 <= W_OUT - 1);
    bool vy0 = (iy0 >= 0) && (iy0 <= H_OUT - 1);
    bool vy1 = (iy1 >= 0) && (iy1 <= H_OUT - 1);
    int cx0 = min(max(ix0, 0), W_OUT - 1);
    int cx1 = min(max(ix1, 0), W_OUT - 1);
    int cy0 = min(max(iy0, 0), H_OUT - 1);
    int cy1 = min(max(iy1, 0), H_OUT - 1);
    float g00 = (1.0f - fwy) * (1.0f - fwx) * ((vx0 && vy0) ? 1.0f : 0.0f);
    float g01 = (1.0f - fwy) * fwx * ((vx1 && vy0) ? 1.0f : 0.0f);
    float g10 = fwy * (1.0f - fwx) * ((vx0 && vy1) ? 1.0f : 0.0f);
    float g11 = fwy * fwx * ((vx1 && vy1) ? 1.0f : 0.0f);

    int o00 = cy0 * W_OUT + cx0;
    int o01 = cy0 * W_OUT + cx1;
    int o10 = cy1 * W_OUT + cx0;
    int o11 = cy1 * W_OUT + cx1;

    const float* ib = image + b * (CH * HW_OUT);
    const float* im0 = ib;
    const float* im1 = ib + HW_OUT;
    const float* im2 = ib + 2 * HW_OUT;

    // 12 independent gathers, then FMA trees
    float p00 = im0[o00], p01 = im0[o01], p10 = im0[o10], p11 = im0[o11];
    float q00 = im1[o00], q01 = im1[o01], q10 = im1[o10], q11 = im1[o11];
    float r00 = im2[o00], r01 = im2[o01], r10 = im2[o10], r11 = im2[o11];

    int op = y * W_OUT + x;
    float* ob = out + b * (CH * HW_OUT);
    ob[op]              = g00 * p00 + g01 * p01 + g10 * p10 + g11 * p11;
    ob[HW_OUT + op]     = g00 * q00 + g01 * q01 + g10 * q10 + g11 * q11;
    ob[2 * HW_OUT + op] = g00 * r00 + g01 * r01 + g10 * r10 + g11 * r11;
}

extern "C" void kernel_launch(void* const* d_in, const int* in_sizes, int n_in,
                              void* d_out, int out_size, void* d_ws, size_t ws_size,
                              hipStream_t stream) {
    const float* image  = (const float*)d_in[0];
    const float* disp   = (const float*)d_in[1];
    const float* scene  = (const float*)d_in[2];
    const float* intrin = (const float*)d_in[3];
    const float* aug    = (const float*)d_in[4];
    float* out = (float*)d_out;

    const int grid = BATCH * CHUNKS_PER_B;  // 15360 blocks
    warp_sceneflow_kernel<<<grid, 256, 0, stream>>>(image, disp, scene, intrin, aug, out);
}

// Round 4
// 91.302 us; speedup vs baseline: 1.6714x; 1.0159x over previous
//
#include <hip/hip_runtime.h>

#define BATCH 8
#define CH 3
#define H_OUT 384
#define W_OUT 1280
#define H_IN 96
#define W_IN 320
#define HW_OUT (H_OUT * W_OUT)
#define HW_IN (H_IN * W_IN)

#define ROWS_PT 2                         // rows per thread (independent ILP chains)
#define SEGS_PER_ROW (W_OUT / 256)        // 5
#define PAIRS (H_OUT / ROWS_PT)           // 192
#define CHUNKS_PER_B (PAIRS * SEGS_PER_ROW)  // 960

__global__ __launch_bounds__(256) void warp_sceneflow_kernel(
    const float* __restrict__ image,   // (B,3,384,1280)
    const float* __restrict__ disp,    // (B,1,96,320)
    const float* __restrict__ scene,   // (B,3,96,320)
    const float* __restrict__ intrin,  // (B,3,3)
    const float* __restrict__ aug,     // (B,2)
    float* __restrict__ out)           // (B,3,384,1280)
{
    // XCD-aware: b = bid&7 pins each batch's 5.9 MB image slice to one XCD L2.
    int bid = blockIdx.x;
    int b = bid & 7;
    int c = bid >> 3;                  // 0..959
    int yp = c / SEGS_PER_ROW;
    int xseg = c - yp * SEGS_PER_ROW;
    int x = xseg * 256 + threadIdx.x;  // wave lanes: 64 consecutive x
    int ybase = yp * ROWS_PT;

    // per-batch scaled intrinsics (block-uniform)
    float sy = (float)H_OUT / aug[b * 2 + 0];
    float sxs = (float)W_OUT / aug[b * 2 + 1];
    float fx = intrin[b * 9 + 0] * sxs;
    float fy = intrin[b * 9 + 4] * sy;
    float cx = intrin[b * 9 + 2] * sxs;
    float cy = intrin[b * 9 + 5] * sy;
    float inv_fx = 1.0f / fx;
    float inv_fy = 1.0f / fy;

    // x-direction low-res interp (shared by both rows)
    float xsrc = (float)x * ((float)(W_IN - 1) / (float)(W_OUT - 1));
    int x0 = (int)xsrc;
    int x1 = min(x0 + 1, W_IN - 1);
    float wx = xsrc - (float)x0;

    const float* db = disp + b * HW_IN;
    const float* s0 = scene + b * (CH * HW_IN);
    const float* s1 = s0 + HW_IN;
    const float* s2 = s0 + 2 * HW_IN;
    const float* ib = image + b * (CH * HW_OUT);
    const float* im0 = ib;
    const float* im1 = ib + HW_OUT;
    const float* im2 = ib + 2 * HW_OUT;

    float g00[ROWS_PT], g01[ROWS_PT], g10[ROWS_PT], g11[ROWS_PT];
    int o00[ROWS_PT], o01[ROWS_PT], o10[ROWS_PT], o11[ROWS_PT];

    #pragma unroll
    for (int r = 0; r < ROWS_PT; ++r) {
        int y = ybase + r;

        float ysrc = (float)y * ((float)(H_IN - 1) / (float)(H_OUT - 1));
        int y0 = (int)ysrc;
        int y1 = min(y0 + 1, H_IN - 1);
        float wy = ysrc - (float)y0;

        int i00 = y0 * W_IN + x0, i01 = y0 * W_IN + x1;
        int i10 = y1 * W_IN + x0, i11 = y1 * W_IN + x1;

        // 16 independent low-res loads (L1/L2-resident)
        float d00 = db[i00], d01 = db[i01], d10 = db[i10], d11 = db[i11];
        float a00 = s0[i00], a01 = s0[i01], a10 = s0[i10], a11 = s0[i11];
        float b00 = s1[i00], b01 = s1[i01], b10 = s1[i10], b11 = s1[i11];
        float e00 = s2[i00], e01 = s2[i01], e10 = s2[i10], e11 = s2[i11];

        float w00 = (1.0f - wy) * (1.0f - wx);
        float w01 = (1.0f - wy) * wx;
        float w10 = wy * (1.0f - wx);
        float w11 = wy * wx;

        float dval = w00 * d00 + w01 * d01 + w10 * d10 + w11 * d11;
        float disp_full = dval * (float)W_OUT;
        float depth = fminf(fmaxf(fx * 0.54f / (disp_full + 1e-8f), 0.001f), 80.0f);

        float sc0 = w00 * a00 + w01 * a01 + w10 * a10 + w11 * a11;
        float sc1 = w00 * b00 + w01 * b01 + w10 * b10 + w11 * b11;
        float sc2 = w00 * e00 + w01 * e01 + w10 * e10 + w11 * e11;

        // backproject + scene flow + reproject
        float X = ((float)x - cx) * inv_fx * depth + sc0;
        float Y = ((float)y - cy) * inv_fy * depth + sc1;
        float Z = depth + sc2;
        float u = fx * X + cx * Z;
        float v = fy * Y + cy * Z;
        float rw = 1.0f / (Z + 1e-8f);
        float coord_x = u * rw;
        float coord_y = v * rw;

        // normalize round-trip (matches reference arithmetic)
        float nx = coord_x / (float)(W_OUT - 1) * 2.0f - 1.0f;
        float ny = coord_y / (float)(H_OUT - 1) * 2.0f - 1.0f;
        float gx = (nx + 1.0f) * 0.5f * (float)(W_OUT - 1);
        float gy = (ny + 1.0f) * 0.5f * (float)(H_OUT - 1);

        // grid sample weights/offsets, zeros padding
        float gx0f = floorf(gx), gy0f = floorf(gy);
        float fwx = gx - gx0f, fwy = gy - gy0f;
        int ix0 = (int)gx0f, iy0 = (int)gy0f;
        int ix1 = ix0 + 1, iy1 = iy0 + 1;
        bool vx0 = (ix0 >= 0) && (ix0 <= W_OUT - 1);
        bool vx1 = (ix1 >= 0) && (ix1 <= W_OUT - 1);
        bool vy0 = (iy0 >= 0) && (iy0 <= H_OUT - 1);
        bool vy1 = (iy1 >= 0) && (iy1 <= H_OUT - 1);
        int cx0 = min(max(ix0, 0), W_OUT - 1);
        int cx1 = min(max(ix1, 0), W_OUT - 1);
        int cy0 = min(max(iy0, 0), H_OUT - 1);
        int cy1 = min(max(iy1, 0), H_OUT - 1);
        g00[r] = (1.0f - fwy) * (1.0f - fwx) * ((vx0 && vy0) ? 1.0f : 0.0f);
        g01[r] = (1.0f - fwy) * fwx * ((vx1 && vy0) ? 1.0f : 0.0f);
        g10[r] = fwy * (1.0f - fwx) * ((vx0 && vy1) ? 1.0f : 0.0f);
        g11[r] = fwy * fwx * ((vx1 && vy1) ? 1.0f : 0.0f);
        o00[r] = cy0 * W_OUT + cx0;
        o01[r] = cy0 * W_OUT + cx1;
        o10[r] = cy1 * W_OUT + cx0;
        o11[r] = cy1 * W_OUT + cx1;
    }

    // 24 independent image gathers across both row-chains
    float res[ROWS_PT][CH];
    #pragma unroll
    for (int r = 0; r < ROWS_PT; ++r) {
        float p00 = im0[o00[r]], p01 = im0[o01[r]], p10 = im0[o10[r]], p11 = im0[o11[r]];
        float q00 = im1[o00[r]], q01 = im1[o01[r]], q10 = im1[o10[r]], q11 = im1[o11[r]];
        float t00 = im2[o00[r]], t01 = im2[o01[r]], t10 = im2[o10[r]], t11 = im2[o11[r]];
        res[r][0] = g00[r] * p00 + g01[r] * p01 + g10[r] * p10 + g11[r] * p11;
        res[r][1] = g00[r] * q00 + g01[r] * q01 + g10[r] * q10 + g11[r] * q11;
        res[r][2] = g00[r] * t00 + g01[r] * t01 + g10[r] * t10 + g11[r] * t11;
    }

    float* ob = out + b * (CH * HW_OUT);
    #pragma unroll
    for (int r = 0; r < ROWS_PT; ++r) {
        int op = (ybase + r) * W_OUT + x;
        __builtin_nontemporal_store(res[r][0], ob + op);
        __builtin_nontemporal_store(res[r][1], ob + HW_OUT + op);
        __builtin_nontemporal_store(res[r][2], ob + 2 * HW_OUT + op);
    }
}

extern "C" void kernel_launch(void* const* d_in, const int* in_sizes, int n_in,
                              void* d_out, int out_size, void* d_ws, size_t ws_size,
                              hipStream_t stream) {
    const float* image  = (const float*)d_in[0];
    const float* disp   = (const float*)d_in[1];
    const float* scene  = (const float*)d_in[2];
    const float* intrin = (const float*)d_in[3];
    const float* aug    = (const float*)d_in[4];
    float* out = (float*)d_out;

    const int grid = BATCH * CHUNKS_PER_B;  // 7680 blocks
    warp_sceneflow_kernel<<<grid, 256, 0, stream>>>(image, disp, scene, intrin, aug, out);
}

// Round 5
// 88.897 us; speedup vs baseline: 1.7166x; 1.0271x over previous
//
#include <hip/hip_runtime.h>

#define BATCH 8
#define CH 3
#define H_OUT 384
#define W_OUT 1280
#define H_IN 96
#define W_IN 320
#define HW_OUT (H_OUT * W_OUT)
#define HW_IN (H_IN * W_IN)

#define ROWS_PT 2                         // rows per thread (independent ILP chains)
#define SEGS_PER_ROW (W_OUT / 256)        // 5
#define PAIRS (H_OUT / ROWS_PT)           // 192
#define CHUNKS_PER_B (PAIRS * SEGS_PER_ROW)  // 960

// 4-byte-aligned float2 so the compiler may emit global_load_dwordx2 without
// assuming 8B alignment (gather bases are arbitrary pixel indices).
struct __attribute__((packed, aligned(4))) f2 { float x, y; };

__global__ __launch_bounds__(256) void warp_sceneflow_kernel(
    const float* __restrict__ image,   // (B,3,384,1280)
    const float* __restrict__ disp,    // (B,1,96,320)
    const float* __restrict__ scene,   // (B,3,96,320)
    const float* __restrict__ intrin,  // (B,3,3)
    const float* __restrict__ aug,     // (B,2)
    float* __restrict__ out)           // (B,3,384,1280)
{
    // XCD-aware: b = bid&7 pins each batch's 5.9 MB image slice to one XCD L2.
    int bid = blockIdx.x;
    int b = bid & 7;
    int c = bid >> 3;                  // 0..959
    int yp = c / SEGS_PER_ROW;
    int xseg = c - yp * SEGS_PER_ROW;
    int x = xseg * 256 + threadIdx.x;  // wave lanes: 64 consecutive x
    int ybase = yp * ROWS_PT;

    // per-batch scaled intrinsics (block-uniform)
    float sy = (float)H_OUT / aug[b * 2 + 0];
    float sxs = (float)W_OUT / aug[b * 2 + 1];
    float fx = intrin[b * 9 + 0] * sxs;
    float fy = intrin[b * 9 + 4] * sy;
    float cx = intrin[b * 9 + 2] * sxs;
    float cy = intrin[b * 9 + 5] * sy;
    float inv_fx = 1.0f / fx;
    float inv_fy = 1.0f / fy;

    // x-direction low-res interp (shared by both rows)
    float xsrc = (float)x * ((float)(W_IN - 1) / (float)(W_OUT - 1));
    int x0 = (int)xsrc;
    int x1 = min(x0 + 1, W_IN - 1);
    float wx = xsrc - (float)x0;
    int xb = min(x0, W_IN - 2);        // float2 base; safe within row
    bool selx = (x0 != xb);            // right-clamped: x0-tap uses .y

    const float* db = disp + b * HW_IN;
    const float* s0 = scene + b * (CH * HW_IN);
    const float* s1 = s0 + HW_IN;
    const float* s2 = s0 + 2 * HW_IN;
    const float* ib = image + b * (CH * HW_OUT);
    const float* im0 = ib;
    const float* im1 = ib + HW_OUT;
    const float* im2 = ib + 2 * HW_OUT;

    float g00[ROWS_PT], g01[ROWS_PT], g10[ROWS_PT], g11[ROWS_PT];
    int rb0[ROWS_PT], rb1[ROWS_PT];
    bool rc[ROWS_PT], lc[ROWS_PT];

    #pragma unroll
    for (int r = 0; r < ROWS_PT; ++r) {
        int y = ybase + r;

        float ysrc = (float)y * ((float)(H_IN - 1) / (float)(H_OUT - 1));
        int y0 = (int)ysrc;
        int y1 = min(y0 + 1, H_IN - 1);
        float wy = ysrc - (float)y0;

        // low-res loads: 8 dwordx2 (pairs x0,x1 share a cache line)
        int r0 = y0 * W_IN + xb;
        int r1 = y1 * W_IN + xb;
        f2 dR0 = *(const f2*)(db + r0); f2 dR1 = *(const f2*)(db + r1);
        f2 aR0 = *(const f2*)(s0 + r0); f2 aR1 = *(const f2*)(s0 + r1);
        f2 bR0 = *(const f2*)(s1 + r0); f2 bR1 = *(const f2*)(s1 + r1);
        f2 eR0 = *(const f2*)(s2 + r0); f2 eR1 = *(const f2*)(s2 + r1);

        float d00 = selx ? dR0.y : dR0.x, d01 = dR0.y;
        float d10 = selx ? dR1.y : dR1.x, d11 = dR1.y;
        float a00 = selx ? aR0.y : aR0.x, a01 = aR0.y;
        float a10 = selx ? aR1.y : aR1.x, a11 = aR1.y;
        float b00 = selx ? bR0.y : bR0.x, b01 = bR0.y;
        float b10 = selx ? bR1.y : bR1.x, b11 = bR1.y;
        float e00 = selx ? eR0.y : eR0.x, e01 = eR0.y;
        float e10 = selx ? eR1.y : eR1.x, e11 = eR1.y;

        float w00 = (1.0f - wy) * (1.0f - wx);
        float w01 = (1.0f - wy) * wx;
        float w10 = wy * (1.0f - wx);
        float w11 = wy * wx;

        float dval = w00 * d00 + w01 * d01 + w10 * d10 + w11 * d11;
        float disp_full = dval * (float)W_OUT;
        float depth = fminf(fmaxf(fx * 0.54f / (disp_full + 1e-8f), 0.001f), 80.0f);

        float sc0 = w00 * a00 + w01 * a01 + w10 * a10 + w11 * a11;
        float sc1 = w00 * b00 + w01 * b01 + w10 * b10 + w11 * b11;
        float sc2 = w00 * e00 + w01 * e01 + w10 * e10 + w11 * e11;

        // backproject + scene flow + reproject
        float X = ((float)x - cx) * inv_fx * depth + sc0;
        float Y = ((float)y - cy) * inv_fy * depth + sc1;
        float Z = depth + sc2;
        float u = fx * X + cx * Z;
        float v = fy * Y + cy * Z;
        float rw = 1.0f / (Z + 1e-8f);
        float coord_x = u * rw;
        float coord_y = v * rw;

        // normalize round-trip (matches reference arithmetic)
        float nx = coord_x / (float)(W_OUT - 1) * 2.0f - 1.0f;
        float ny = coord_y / (float)(H_OUT - 1) * 2.0f - 1.0f;
        float gx = (nx + 1.0f) * 0.5f * (float)(W_OUT - 1);
        float gy = (ny + 1.0f) * 0.5f * (float)(H_OUT - 1);

        // grid sample weights/offsets, zeros padding
        float gx0f = floorf(gx), gy0f = floorf(gy);
        float fwx = gx - gx0f, fwy = gy - gy0f;
        int ix0 = (int)gx0f, iy0 = (int)gy0f;
        int ix1 = ix0 + 1, iy1 = iy0 + 1;
        bool vx0 = (ix0 >= 0) && (ix0 <= W_OUT - 1);
        bool vx1 = (ix1 >= 0) && (ix1 <= W_OUT - 1);
        bool vy0 = (iy0 >= 0) && (iy0 <= H_OUT - 1);
        bool vy1 = (iy1 >= 0) && (iy1 <= H_OUT - 1);
        int cx0 = min(max(ix0, 0), W_OUT - 1);
        int cx1 = min(max(ix1, 0), W_OUT - 1);
        int cy0 = min(max(iy0, 0), H_OUT - 1);
        int cy1 = min(max(iy1, 0), H_OUT - 1);
        g00[r] = (1.0f - fwy) * (1.0f - fwx) * ((vx0 && vy0) ? 1.0f : 0.0f);
        g01[r] = (1.0f - fwy) * fwx * ((vx1 && vy0) ? 1.0f : 0.0f);
        g10[r] = fwy * (1.0f - fwx) * ((vx0 && vy1) ? 1.0f : 0.0f);
        g11[r] = fwy * fwx * ((vx1 && vy1) ? 1.0f : 0.0f);

        // float2 gather bases: taps (x0,x1) merged into one dwordx2 per row
        int xbi = min(cx0, W_OUT - 2);
        rc[r] = (cx0 != xbi);     // right clamp: x0-tap is .y
        lc[r] = (cx1 == xbi);     // left clamp: x1-tap is .x
        rb0[r] = cy0 * W_OUT + xbi;
        rb1[r] = cy1 * W_OUT + xbi;
    }

    // 12 independent dwordx2 image gathers (was 24 dword)
    float res[ROWS_PT][CH];
    #pragma unroll
    for (int r = 0; r < ROWS_PT; ++r) {
        f2 P0 = *(const f2*)(im0 + rb0[r]); f2 P1 = *(const f2*)(im0 + rb1[r]);
        f2 Q0 = *(const f2*)(im1 + rb0[r]); f2 Q1 = *(const f2*)(im1 + rb1[r]);
        f2 T0 = *(const f2*)(im2 + rb0[r]); f2 T1 = *(const f2*)(im2 + rb1[r]);
        float p00 = rc[r] ? P0.y : P0.x, p01 = lc[r] ? P0.x : P0.y;
        float p10 = rc[r] ? P1.y : P1.x, p11 = lc[r] ? P1.x : P1.y;
        float q00 = rc[r] ? Q0.y : Q0.x, q01 = lc[r] ? Q0.x : Q0.y;
        float q10 = rc[r] ? Q1.y : Q1.x, q11 = lc[r] ? Q1.x : Q1.y;
        float t00 = rc[r] ? T0.y : T0.x, t01 = lc[r] ? T0.x : T0.y;
        float t10 = rc[r] ? T1.y : T1.x, t11 = lc[r] ? T1.x : T1.y;
        res[r][0] = g00[r] * p00 + g01[r] * p01 + g10[r] * p10 + g11[r] * p11;
        res[r][1] = g00[r] * q00 + g01[r] * q01 + g10[r] * q10 + g11[r] * q11;
        res[r][2] = g00[r] * t00 + g01[r] * t01 + g10[r] * t10 + g11[r] * t11;
    }

    float* ob = out + b * (CH * HW_OUT);
    #pragma unroll
    for (int r = 0; r < ROWS_PT; ++r) {
        int op = (ybase + r) * W_OUT + x;
        __builtin_nontemporal_store(res[r][0], ob + op);
        __builtin_nontemporal_store(res[r][1], ob + HW_OUT + op);
        __builtin_nontemporal_store(res[r][2], ob + 2 * HW_OUT + op);
    }
}

extern "C" void kernel_launch(void* const* d_in, const int* in_sizes, int n_in,
                              void* d_out, int out_size, void* d_ws, size_t ws_size,
                              hipStream_t stream) {
    const float* image  = (const float*)d_in[0];
    const float* disp   = (const float*)d_in[1];
    const float* scene  = (const float*)d_in[2];
    const float* intrin = (const float*)d_in[3];
    const float* aug    = (const float*)d_in[4];
    float* out = (float*)d_out;

    const int grid = BATCH * CHUNKS_PER_B;  // 7680 blocks
    warp_sceneflow_kernel<<<grid, 256, 0, stream>>>(image, disp, scene, intrin, aug, out);
}